// Round 16
// baseline (77.799 us; speedup 1.0000x reference)
//
#include <hip/hip_runtime.h>
#include <hip/hip_bf16.h>

// QLSTM: T=512, B=256, D_IN=128, D_H=128.
// Gates are per-batch SCALARS broadcast over hidden dim => h,c uniform across
// hidden dim. comb@W[0] = x@W[0][:128] + h*sum(W[0][128:]).
// R15 post-mortem: scan = 192cy/step, ~80 issue + ~110 exposed chain latency;
// a single in-order wave can't fill its own stalls. R16: TWO scan waves per
// SIMD (512-thread blocks; waves 0 and 4 land on SIMD0 under round-robin
// wave->SIMD mapping) so the HW scheduler fills each wave's stalls with the
// other wave's issue. 16 blocks x 16 batches, z staged in 128KB LDS.

constexpr int T = 512;
constexpr int Bsz = 256;
constexpr int R = T * Bsz;          // 131072 rows
constexpr float INV2PI = 0.15915494309189535f;

typedef float f4v __attribute__((ext_vector_type(4)));

// ---------------- Kernel 1: xz[row] = float4(zf,zi,zu,zo)/(2pi), row = t*B+b
__global__ __launch_bounds__(256) void xz_kernel(
    const float* __restrict__ x,
    const float* __restrict__ Wf, const float* __restrict__ bf, const float* __restrict__ tf,
    const float* __restrict__ Wi, const float* __restrict__ bi, const float* __restrict__ ti,
    const float* __restrict__ Wu, const float* __restrict__ bu, const float* __restrict__ tu,
    const float* __restrict__ Wo, const float* __restrict__ bo, const float* __restrict__ to_,
    float4* __restrict__ xz)
{
    const int wglobal = blockIdx.x * 4 + (threadIdx.x >> 6);   // 0..8191
    const int lane = threadIdx.x & 63;
    const int hl = lane & 31;            // lane within half-wave
    const int half = lane >> 5;          // which row of the pair

    const float4 wfv = ((const float4*)Wf)[hl];
    const float4 wiv = ((const float4*)Wi)[hl];
    const float4 wuv = ((const float4*)Wu)[hl];
    const float4 wov = ((const float4*)Wo)[hl];

    const float cf = bf[0] + tf[0];
    const float ci = bi[0] + ti[0];
    const float cu = bu[0] + tu[0];
    const float co = bo[0] + to_[0];

    for (int it = 0; it < 8; ++it) {
        const int row = (it * 8192 + wglobal) * 2 + half;
        const float4 xv = *(const float4*)(x + (size_t)row * 128 + hl * 4);

        float pf = xv.x * wfv.x + xv.y * wfv.y + xv.z * wfv.z + xv.w * wfv.w;
        float pi = xv.x * wiv.x + xv.y * wiv.y + xv.z * wiv.z + xv.w * wiv.w;
        float pu = xv.x * wuv.x + xv.y * wuv.y + xv.z * wuv.z + xv.w * wuv.w;
        float po = xv.x * wov.x + xv.y * wov.y + xv.z * wov.z + xv.w * wov.w;

#pragma unroll
        for (int off = 16; off; off >>= 1) {
            pf += __shfl_xor(pf, off, 64);
            pi += __shfl_xor(pi, off, 64);
            pu += __shfl_xor(pu, off, 64);
            po += __shfl_xor(po, off, 64);
        }
        if (hl == 0) {
            xz[row] = make_float4((pf + cf) * INV2PI, (pi + ci) * INV2PI,
                                  (pu + cu) * INV2PI, (po + co) * INV2PI);
        }
    }
}

// ---------------- Kernel 2: scan, 2 scan waves per SIMD.
// tanh(c), |c|<=2.07 (provable bound): odd deg-9 polynomial (no rcp),
// err ~1e-3 typ, <=5e-3 near endpoint.
__device__ __forceinline__ float tanh9(float c) {
    const float y  = c * c;
    const float y2 = y * y;
    const float lo  = fmaf(y, -0.321470f, 0.999168f);
    const float hi  = fmaf(y, 0.0016407f, -0.0199491f);
    const float mid = fmaf(y, hi, 0.101498f);
    return c * fmaf(y2, mid, lo);
}

template<int CTRL>
__device__ __forceinline__ float dppq(float x) {
    return __builtin_bit_cast(float,
        __builtin_amdgcn_mov_dpp(__builtin_bit_cast(int, x), CTRL, 0xF, 0xF, true));
}

__device__ __forceinline__ float wsum(const float* __restrict__ W, int lane) {
    float s = W[128 + lane] + W[192 + lane];
#pragma unroll
    for (int off = 32; off; off >>= 1) s += __shfl_xor(s, off, 64);
    return s;  // butterfly: all lanes hold the sum
}

constexpr int BPB = 16;                  // batches per block (2 scan waves x 8)
constexpr int SCAN_BLOCKS = Bsz / BPB;   // 16

__global__ __launch_bounds__(512, 1) void scan_kernel(
    const float4* __restrict__ xz,
    const float* __restrict__ Wf, const float* __restrict__ Wi,
    const float* __restrict__ Wu, const float* __restrict__ Wo,
    float* __restrict__ hscan, float* __restrict__ cfin)
{
    __shared__ float4 zb4[T * BPB];      // 128 KB z slice, [t][bg 0..15] float4
    const int tid = threadIdx.x;
    const int bb = blockIdx.x * BPB;
    const int wv = tid >> 6;             // wave 0..7; waves 0 and 4 -> SIMD0
    const int l  = tid & 63;

    // ---- stage the entire z slice: 512 threads x 16 float4 loads
#pragma unroll
    for (int k = 0; k < T * BPB / 512; ++k) {      // 16 iterations
        const int j = k * 512 + tid;               // 0..8191
        zb4[j] = xz[(j >> 4) * Bsz + bb + (j & 15)];
    }

    // ---- per-gate hidden-weight sums (only scan waves need them)
    float swf = 0, swi = 0, swu = 0, swo = 0;
    if ((wv & 3) == 0) {                 // waves 0 and 4
        swf = wsum(Wf, l) * INV2PI;
        swi = wsum(Wi, l) * INV2PI;
        swu = wsum(Wu, l) * INV2PI;
        swo = wsum(Wo, l) * INV2PI;
    }

    __syncthreads();                     // z slice ready; helper waves done after this

    if ((wv & 3) != 0 || l >= 32) return;

    // scan lanes: wave 0 -> batches bb..bb+7, wave 4 -> bb+8..bb+15
    const int g = wv >> 2;               // 0 or 1
    const int q = l & 3;                 // gate: 0=f 1=i 2=g(tanh) 3=o
    const int bgl = g * 8 + (l >> 2);    // batch-in-block 0..15
    const int batch = bb + bgl;

    const float sw = (q == 0) ? swf : (q == 1) ? swi : (q == 2) ? swu : swo;

    // deg-5 odd gate polynomial in v = cos(u):
    //   tanh lane (q==2): tanh(v) (err ~1.5e-3);
    //   sigmoid lanes: 0.5 + 0.5*tanh(v/2) folded (err ~1.1e-4).
    const bool tq = (q == 2);
    const float K0 = tq ? 0.0f       : 0.5f;
    const float K1 = tq ? 0.999318f  : 0.249976f;
    const float K3 = tq ? -0.319476f : -0.0206916f;
    const float K5 = tq ? 0.08315f   : 0.00188244f;

    const float* zl = (const float*)zb4 + bgl * 4 + q;   // scalar [t*64 + bgl*4 + q]
    float* hp = hscan + batch;

    // carried state: c, tc = tanh9(c), os = o*sw  (h = o*tc off-path for store)
    float c = 0.0f, tc = 0.0f, os = 0.0f;

// serial cycle: u -> cos -> v2 -> t1 -> p -> gown -> dpp -> ig -> cfma ->
// tanh9 -> u(next).  os = o*sw and the h store run parallel to tanh9.
#define HSTEP(Y)                                                   \
    {                                                              \
        const float u  = fmaf(tc, os, (Y));                        \
        const float v  = __builtin_amdgcn_cosf(u);                 \
        const float v2 = v * v;                                    \
        const float t1 = fmaf(v2, K5, K3);                         \
        const float p  = fmaf(v2, t1, K1);                         \
        const float gown = fmaf(v, p, K0);                         \
        const float f = dppq<0x00>(gown);                          \
        const float i = dppq<0x55>(gown);                          \
        const float g_ = dppq<0xAA>(gown);                         \
        const float o = dppq<0xFF>(gown);                          \
        c  = fmaf(f, c, i * g_);                                   \
        tc = tanh9(c);                                             \
        os = o * sw;                                               \
        *hp = o * tc;                                              \
        hp += Bsz;                                                 \
    }

    // group-ahead prefetch: next 8-step z-group read into named regs BEFORE
    // the current group is consumed (first-use lgkmcnt covered by 8 steps).
    float p0 = zl[0 * 64], p1 = zl[1 * 64], p2 = zl[2 * 64], p3 = zl[3 * 64];
    float p4 = zl[4 * 64], p5 = zl[5 * 64], p6 = zl[6 * 64], p7 = zl[7 * 64];

    for (int tb = 0; tb < T - 8; tb += 8) {
        const float* zn = zl + (size_t)(tb + 8) * 64;
        const float n0 = zn[0 * 64];
        const float n1 = zn[1 * 64];
        const float n2 = zn[2 * 64];
        const float n3 = zn[3 * 64];
        const float n4 = zn[4 * 64];
        const float n5 = zn[5 * 64];
        const float n6 = zn[6 * 64];
        const float n7 = zn[7 * 64];
        HSTEP(p0); HSTEP(p1); HSTEP(p2); HSTEP(p3);
        HSTEP(p4); HSTEP(p5); HSTEP(p6); HSTEP(p7);
        p0 = n0; p1 = n1; p2 = n2; p3 = n3;
        p4 = n4; p5 = n5; p6 = n6; p7 = n7;
    }
    // epilogue group
    HSTEP(p0); HSTEP(p1); HSTEP(p2); HSTEP(p3);
    HSTEP(p4); HSTEP(p5); HSTEP(p6); HSTEP(p7);
#undef HSTEP

    cfin[batch] = c;                     // 4 quad lanes, same value, same addr
}

// ---------------- Kernel 3: broadcast h[t,b] across 128 hidden cols, + hx/cx tails.
__global__ __launch_bounds__(256) void bcast_kernel(
    const float* __restrict__ hscan, const float* __restrict__ cfin,
    float4* __restrict__ out)
{
    const unsigned i = blockIdx.x * 256u + threadIdx.x;  // float4 index
    const unsigned row = i >> 5;                          // output row (128 floats)
    float v;
    if (row < (unsigned)R) {
        v = hscan[row];
    } else {
        const unsigned r2 = row - (unsigned)R;
        v = (r2 < (unsigned)Bsz) ? hscan[(T - 1) * Bsz + r2] : cfin[r2 - (unsigned)Bsz];
    }
    const f4v val = {v, v, v, v};
    __builtin_nontemporal_store(val, (f4v*)&out[i]);     // write-only stream
}

extern "C" void kernel_launch(void* const* d_in, const int* in_sizes, int n_in,
                              void* d_out, int out_size, void* d_ws, size_t ws_size,
                              hipStream_t stream)
{
    const float* x  = (const float*)d_in[0];
    const float* Wf = (const float*)d_in[1];
    const float* bf = (const float*)d_in[2];
    const float* tf = (const float*)d_in[3];
    const float* Wi = (const float*)d_in[4];
    const float* bi = (const float*)d_in[5];
    const float* ti = (const float*)d_in[6];
    const float* Wu = (const float*)d_in[7];
    const float* bu = (const float*)d_in[8];
    const float* tu = (const float*)d_in[9];
    const float* Wo = (const float*)d_in[10];
    const float* bo = (const float*)d_in[11];
    const float* to_ = (const float*)d_in[12];

    float* ws    = (float*)d_ws;
    float4* xz   = (float4*)ws;       // R float4s  (4*R floats)
    float* hscan = ws + 4 * R;        // R floats
    float* cfin  = ws + 5 * R;        // Bsz floats

    xz_kernel<<<2048, 256, 0, stream>>>(x, Wf, bf, tf, Wi, bi, ti, Wu, bu, tu, Wo, bo, to_, xz);
    scan_kernel<<<SCAN_BLOCKS, 512, 0, stream>>>(xz, Wf, Wi, Wu, Wo, hscan, cfin);

    const int total_f4 = (R + 2 * Bsz) * 32;              // 4,210,688
    bcast_kernel<<<total_f4 / 256, 256, 0, stream>>>(hscan, cfin, (float4*)d_out);
}

// Round 17
// 60.146 us; speedup vs baseline: 1.2935x; 1.2935x over previous
//
#include <hip/hip_runtime.h>
#include <hip/hip_bf16.h>

// QLSTM: T=512, B=256, D_IN=128, D_H=128.
// Gates are per-batch SCALARS broadcast over hidden dim => h,c uniform across
// hidden dim. comb@W[0] = x@W[0][:128] + h*sum(W[0][128:]).
// R16 post-mortem: scan floor = 512 x ~190cy chain (TLP can't fill it).
// R17: t-chunked SOFTWARE PIPELINE ACROSS KERNEL LAUNCHES. pipe_kernel(k):
//   blocks 0-31  : scan chunk k (R15 math; h/c state via workspace)
//   blocks 32+   : xz GEMV chunk k+1  +  bcast-write chunk k-1 (grid-stride)
// Kernel boundaries provide the producer->consumer sync; the 67MB read and
// 67MB write ride under the 4 x 10.2us chunk scans. 6 launches, k=-1..4.

constexpr int T = 512;
constexpr int Bsz = 256;
constexpr int R = T * Bsz;          // 131072 rows
constexpr int CH = 128;             // timesteps per chunk
constexpr int NCH = T / CH;         // 4
constexpr int MEMB = 2016;          // memory-role blocks
constexpr int GRID = 32 + MEMB;     // 2048
constexpr float INV2PI = 0.15915494309189535f;

typedef float f4v __attribute__((ext_vector_type(4)));

// tanh(c), |c|<=2.07 (provable bound): odd deg-9 polynomial (no rcp),
// err ~1e-3 typ, <=5e-3 near endpoint.
__device__ __forceinline__ float tanh9(float c) {
    const float y  = c * c;
    const float y2 = y * y;
    const float lo  = fmaf(y, -0.321470f, 0.999168f);
    const float hi  = fmaf(y, 0.0016407f, -0.0199491f);
    const float mid = fmaf(y, hi, 0.101498f);
    return c * fmaf(y2, mid, lo);
}

template<int CTRL>
__device__ __forceinline__ float dppq(float x) {
    return __builtin_bit_cast(float,
        __builtin_amdgcn_mov_dpp(__builtin_bit_cast(int, x), CTRL, 0xF, 0xF, true));
}

__device__ __forceinline__ float wsum(const float* __restrict__ W, int lane) {
    float s = W[128 + lane] + W[192 + lane];
#pragma unroll
    for (int off = 32; off; off >>= 1) s += __shfl_xor(s, off, 64);
    return s;  // butterfly: all lanes hold the sum
}

__global__ __launch_bounds__(256) void pipe_kernel(
    const int k,
    const float* __restrict__ x,
    const float* __restrict__ Wf, const float* __restrict__ bf, const float* __restrict__ tf,
    const float* __restrict__ Wi, const float* __restrict__ bi, const float* __restrict__ ti,
    const float* __restrict__ Wu, const float* __restrict__ bu, const float* __restrict__ tu,
    const float* __restrict__ Wo, const float* __restrict__ bo, const float* __restrict__ to_,
    float4* __restrict__ xz, float* __restrict__ hscan,
    float* __restrict__ hstate, float* __restrict__ cstate,
    float4* __restrict__ out4)
{
    const int tid = threadIdx.x;

    if (blockIdx.x < 32) {
        // ================= scan role: chunk k =================
        if (k < 0 || k >= NCH) return;
        __shared__ float4 zb4[CH * 8];       // 16 KB, [t_local][bg]
        const int bb = blockIdx.x * 8;
        const int cb = k * CH;

        // stage the chunk z slice: 256 threads x 4 float4 loads
#pragma unroll
        for (int it = 0; it < CH * 8 / 256; ++it) {
            const int j = it * 256 + tid;    // 0..1023
            zb4[j] = xz[(size_t)(cb + (j >> 3)) * Bsz + bb + (j & 7)];
        }

        const int l = tid & 63;
        const float swf = wsum(Wf, l) * INV2PI;
        const float swi = wsum(Wi, l) * INV2PI;
        const float swu = wsum(Wu, l) * INV2PI;
        const float swo = wsum(Wo, l) * INV2PI;

        __syncthreads();
        if (tid >= 32) return;               // lanes 0..31 of wave 0 scan

        const int q = tid & 3;               // gate: 0=f 1=i 2=g(tanh) 3=o
        const int batch = bb + (tid >> 2);

        const float sw = (q == 0) ? swf : (q == 1) ? swi : (q == 2) ? swu : swo;

        // deg-5 odd gate polynomial in v = cos(u):
        //   tanh lane (q==2): tanh(v) (err ~1.5e-3);
        //   sigmoid lanes: 0.5 + 0.5*tanh(v/2) folded (err ~1.1e-4).
        const bool tq = (q == 2);
        const float K0 = tq ? 0.0f       : 0.5f;
        const float K1 = tq ? 0.999318f  : 0.249976f;
        const float K3 = tq ? -0.319476f : -0.0206916f;
        const float K5 = tq ? 0.08315f   : 0.00188244f;

        const float* zl = (const float*)zb4 + tid;   // scalar [t*32 + bg*4 + q]
        float* hp = hscan + (size_t)cb * Bsz + batch;

        float h, c;
        if (k == 0) { h = 0.0f; c = 0.0f; }
        else        { h = hstate[batch]; c = cstate[batch]; }

#define HSTEP(Y)                                                   \
    {                                                              \
        const float u  = fmaf(h, sw, (Y));                         \
        const float v  = __builtin_amdgcn_cosf(u);                 \
        const float v2 = v * v;                                    \
        const float t1 = fmaf(v2, K5, K3);                         \
        const float p  = fmaf(v2, t1, K1);                         \
        const float gown = fmaf(v, p, K0);                         \
        const float f  = dppq<0x00>(gown);                         \
        const float i  = dppq<0x55>(gown);                         \
        const float g_ = dppq<0xAA>(gown);                         \
        const float o  = dppq<0xFF>(gown);                         \
        c = fmaf(f, c, i * g_);                                    \
        h = o * tanh9(c);                                          \
        *hp = h;                                                   \
        hp += Bsz;                                                 \
    }

        // group-ahead prefetch: next 8-step z-group read into named regs
        // BEFORE the current group is consumed.
        float p0 = zl[0 * 32], p1 = zl[1 * 32], p2 = zl[2 * 32], p3 = zl[3 * 32];
        float p4 = zl[4 * 32], p5 = zl[5 * 32], p6 = zl[6 * 32], p7 = zl[7 * 32];

        for (int tb = 0; tb < CH - 8; tb += 8) {
            const float* zn = zl + (size_t)(tb + 8) * 32;
            const float n0 = zn[0 * 32];
            const float n1 = zn[1 * 32];
            const float n2 = zn[2 * 32];
            const float n3 = zn[3 * 32];
            const float n4 = zn[4 * 32];
            const float n5 = zn[5 * 32];
            const float n6 = zn[6 * 32];
            const float n7 = zn[7 * 32];
            HSTEP(p0); HSTEP(p1); HSTEP(p2); HSTEP(p3);
            HSTEP(p4); HSTEP(p5); HSTEP(p6); HSTEP(p7);
            p0 = n0; p1 = n1; p2 = n2; p3 = n3;
            p4 = n4; p5 = n5; p6 = n6; p7 = n7;
        }
        HSTEP(p0); HSTEP(p1); HSTEP(p2); HSTEP(p3);
        HSTEP(p4); HSTEP(p5); HSTEP(p6); HSTEP(p7);
#undef HSTEP

        hstate[batch] = h;                   // quad lanes: same value, same addr
        cstate[batch] = c;
        return;
    }

    // ================= memory role =================
    const int mb   = blockIdx.x - 32;        // 0..MEMB-1
    const int wv   = tid >> 6;
    const int lane = tid & 63;
    const int hl   = lane & 31;
    const int half = lane >> 5;

    // ---- xz GEMV for chunk k+1 (rows [(k+1)*CH*Bsz, +CH*Bsz))
    if (k + 1 < NCH) {
        const float4 wfv = ((const float4*)Wf)[hl];
        const float4 wiv = ((const float4*)Wi)[hl];
        const float4 wuv = ((const float4*)Wu)[hl];
        const float4 wov = ((const float4*)Wo)[hl];
        const float cf = bf[0] + tf[0];
        const float ci = bi[0] + ti[0];
        const float cu = bu[0] + tu[0];
        const float co = bo[0] + to_[0];

        const int slab = (k + 1) * CH * Bsz;
        for (int p = mb * 4 + wv; p < CH * Bsz / 2; p += MEMB * 4) {
            const int row = slab + 2 * p + half;
            const float4 xv = *(const float4*)(x + (size_t)row * 128 + hl * 4);

            float pf = xv.x * wfv.x + xv.y * wfv.y + xv.z * wfv.z + xv.w * wfv.w;
            float pi = xv.x * wiv.x + xv.y * wiv.y + xv.z * wiv.z + xv.w * wiv.w;
            float pu = xv.x * wuv.x + xv.y * wuv.y + xv.z * wuv.z + xv.w * wuv.w;
            float po = xv.x * wov.x + xv.y * wov.y + xv.z * wov.z + xv.w * wov.w;

#pragma unroll
            for (int off = 16; off; off >>= 1) {
                pf += __shfl_xor(pf, off, 64);
                pi += __shfl_xor(pi, off, 64);
                pu += __shfl_xor(pu, off, 64);
                po += __shfl_xor(po, off, 64);
            }
            if (hl == 0) {
                xz[row] = make_float4((pf + cf) * INV2PI, (pi + ci) * INV2PI,
                                      (pu + cu) * INV2PI, (po + co) * INV2PI);
            }
        }
    }

    // ---- bcast-write for chunk k-1 (out rows [(k-1)*CH*Bsz, +CH*Bsz))
    if (k >= 1 && k <= NCH) {
        const int slabr = (k - 1) * CH * Bsz;
        for (int j = mb * 256 + tid; j < CH * Bsz * 32; j += MEMB * 256) {
            const int row = slabr + (j >> 5);
            const float v = hscan[row];
            const f4v val = {v, v, v, v};
            __builtin_nontemporal_store(val, (f4v*)&out4[(size_t)row * 32 + (j & 31)]);
        }
    }

    // ---- tails (hx, cx) in the final launch
    if (k == NCH) {
        for (int j = mb * 256 + tid; j < 2 * Bsz * 32; j += MEMB * 256) {
            const int kind = j >> 13;        // 0 = hx, 1 = cx  (8192 f4 each)
            const int r    = (j >> 5) & 255;
            const int col  = j & 31;
            const float v = kind ? cstate[r] : hscan[(size_t)(T - 1) * Bsz + r];
            const f4v val = {v, v, v, v};
            __builtin_nontemporal_store(
                val, (f4v*)&out4[((size_t)R + (size_t)kind * Bsz + r) * 32 + col]);
        }
    }
}

extern "C" void kernel_launch(void* const* d_in, const int* in_sizes, int n_in,
                              void* d_out, int out_size, void* d_ws, size_t ws_size,
                              hipStream_t stream)
{
    const float* x  = (const float*)d_in[0];
    const float* Wf = (const float*)d_in[1];
    const float* bf = (const float*)d_in[2];
    const float* tf = (const float*)d_in[3];
    const float* Wi = (const float*)d_in[4];
    const float* bi = (const float*)d_in[5];
    const float* ti = (const float*)d_in[6];
    const float* Wu = (const float*)d_in[7];
    const float* bu = (const float*)d_in[8];
    const float* tu = (const float*)d_in[9];
    const float* Wo = (const float*)d_in[10];
    const float* bo = (const float*)d_in[11];
    const float* to_ = (const float*)d_in[12];

    float* ws     = (float*)d_ws;
    float4* xz    = (float4*)ws;          // R float4s (4*R floats)
    float* hscan  = ws + 4 * R;           // R floats
    float* hstate = ws + 5 * R;           // Bsz floats
    float* cstate = ws + 5 * R + Bsz;     // Bsz floats

    for (int k = -1; k <= NCH; ++k) {
        pipe_kernel<<<GRID, 256, 0, stream>>>(
            k, x, Wf, bf, tf, Wi, bi, ti, Wu, bu, tu, Wo, bo, to_,
            xz, hscan, hstate, cstate, (float4*)d_out);
    }
}